// Round 4
// baseline (70.759 us; speedup 1.0000x reference)
//
#include <hip/hip_runtime.h>

// GraphAggrMLPv2: out[n,m,h] = relu(zW1[n,h] + (x^T W2)[m,h] + b[h])
//   z:[8192,128] x:[128,128] W:[256,4] b:[4] fp32 -> out:[8192,128,4] fp32
// Two-kernel plan (dur_us floor is harness 256MiB ws-poison fill ~41us;
// kernel share should be ~6us):
//   k1: zw[n] = z[n,:]@W1 (512 blocks, 16 rows each); block 0 also t[m]=x^T W2+b
//   k2: out4[n][m] = relu(zw4[n] + t4[m])  -- pure streaming write, 1024 blocks

union F4 { float4 v; float f[4]; };

// LDS bank swizzle for W rows (stage-1 reads are d-strided float4s).
__device__ __forceinline__ int sw(int r) { return r + (r >> 3); }

__global__ void __launch_bounds__(256) gam_stage1(
    const float* __restrict__ z, const float* __restrict__ x,
    const float* __restrict__ W, const float* __restrict__ b,
    float4* __restrict__ zw_ws, float4* __restrict__ t_ws)
{
    __shared__ float4 Wf[292];        // swizzled [256 rows][4 heads]
    __shared__ float4 tpart[2][128];  // xW partials (block 0 only)

    const int t   = threadIdx.x;
    const int blk = blockIdx.x;

    // block's z slice: 16 rows x 128 = 512 float4; chunk c: row=c>>5, d4=c&31
    const float4* zp = (const float4*)(z + (size_t)blk * 16 * 128);
    F4 a0, a1;
    a0.v = zp[t];          // rows 0..7
    a1.v = zp[t + 256];    // rows 8..15

    Wf[sw(t)] = ((const float4*)W)[t];
    __syncthreads();

    // zW: lane's chunk covers z[row][d0..d0+3]; 32 lanes (same t>>5) share a row
    {
        const int d0 = (t & 31) * 4;
        float4 p0 = make_float4(0.f,0.f,0.f,0.f);
        float4 p1 = make_float4(0.f,0.f,0.f,0.f);
#pragma unroll
        for (int j = 0; j < 4; ++j) {
            float4 w = Wf[sw(d0 + j)];   // W1 rows
            p0.x = fmaf(a0.f[j], w.x, p0.x); p0.y = fmaf(a0.f[j], w.y, p0.y);
            p0.z = fmaf(a0.f[j], w.z, p0.z); p0.w = fmaf(a0.f[j], w.w, p0.w);
            p1.x = fmaf(a1.f[j], w.x, p1.x); p1.y = fmaf(a1.f[j], w.y, p1.y);
            p1.z = fmaf(a1.f[j], w.z, p1.z); p1.w = fmaf(a1.f[j], w.w, p1.w);
        }
#pragma unroll
        for (int off = 16; off; off >>= 1) {   // stays within 32-lane row-groups
            p0.x += __shfl_xor(p0.x, off); p0.y += __shfl_xor(p0.y, off);
            p0.z += __shfl_xor(p0.z, off); p0.w += __shfl_xor(p0.w, off);
            p1.x += __shfl_xor(p1.x, off); p1.y += __shfl_xor(p1.y, off);
            p1.z += __shfl_xor(p1.z, off); p1.w += __shfl_xor(p1.w, off);
        }
        if ((t & 31) == 0) {
            const int r = t >> 5;        // 0..7
            zw_ws[blk * 16 + r]     = p0;
            zw_ws[blk * 16 + r + 8] = p1;
        }
    }

    // block 0 additionally computes t[m] = sum_d x[d][m]*W2[d][h] + b
    if (blk == 0) {
        const int m    = t & 127;
        const int half = t >> 7;
        const float* xp = x + (size_t)(half * 64) * 128 + m;
        float4 acc = make_float4(0.f, 0.f, 0.f, 0.f);
#pragma unroll 8
        for (int dd = 0; dd < 64; ++dd) {
            float  xv = xp[dd * 128];                  // coalesced across m
            float4 w  = Wf[sw(128 + half * 64 + dd)];  // wave-uniform broadcast
            acc.x = fmaf(xv, w.x, acc.x);
            acc.y = fmaf(xv, w.y, acc.y);
            acc.z = fmaf(xv, w.z, acc.z);
            acc.w = fmaf(xv, w.w, acc.w);
        }
        tpart[half][m] = acc;
        __syncthreads();                                // block-uniform branch: legal
        if (t < 128) {
            float4 bv = *(const float4*)b;
            float4 q0 = tpart[0][t];
            float4 q1 = tpart[1][t];
            float4 tv;
            tv.x = q0.x + q1.x + bv.x;
            tv.y = q0.y + q1.y + bv.y;
            tv.z = q0.z + q1.z + bv.z;
            tv.w = q0.w + q1.w + bv.w;
            t_ws[t] = tv;
        }
    }
}

// k2: out4[c] with c = blk*1024 + it*256 + t; m = t&127 (loop-invariant),
// n = blk*8 + it*2 + (t>>7) (wave-uniform -> broadcast load).
__global__ void __launch_bounds__(256) gam_stage2(
    const float4* __restrict__ zw_ws, const float4* __restrict__ t_ws,
    float4* __restrict__ out4)
{
    const int t   = threadIdx.x;
    const int blk = blockIdx.x;
    const float4  tq = t_ws[t & 127];          // coalesced, L2-resident 2KiB
    const float4* zb = zw_ws + (size_t)blk * 8;
    float4* op = out4 + (size_t)blk * 1024;
#pragma unroll
    for (int it = 0; it < 4; ++it) {
        const int row = it * 2 + (t >> 7);
        float4 s = zb[row];                    // wave-uniform broadcast
        float4 v;
        v.x = fmaxf(tq.x + s.x, 0.f);
        v.y = fmaxf(tq.y + s.y, 0.f);
        v.z = fmaxf(tq.z + s.z, 0.f);
        v.w = fmaxf(tq.w + s.w, 0.f);
        op[it * 256 + t] = v;                  // 16B coalesced store
    }
}

extern "C" void kernel_launch(void* const* d_in, const int* in_sizes, int n_in,
                              void* d_out, int out_size, void* d_ws, size_t ws_size,
                              hipStream_t stream) {
    const float* z = (const float*)d_in[0];
    const float* x = (const float*)d_in[1];
    const float* W = (const float*)d_in[2];
    const float* b = (const float*)d_in[3];
    float4* zw_ws = (float4*)d_ws;             // 8192 float4 = 128 KiB
    float4* t_ws  = (float4*)d_ws + 8192;      // 128 float4 = 2 KiB
    gam_stage1<<<512, 256, 0, stream>>>(z, x, W, b, zw_ws, t_ws);
    gam_stage2<<<1024, 256, 0, stream>>>(zw_ws, t_ws, (float4*)d_out);
}

// Round 5
// 69.527 us; speedup vs baseline: 1.0177x; 1.0177x over previous
//
#include <hip/hip_runtime.h>

// GraphAggrMLPv2: out[n,m,h] = relu(zW1[n,h] + (x^T W2)[m,h] + b[h])
//   z:[8192,128] x:[128,128] W:[256,4] b:[4] fp32 -> out:[8192,128,4] fp32
// Measured: dur_us window is dominated by harness ops (256MiB ws poison
// ~41.4us @81% HBM peak + out poison + restores + graph dispatch overhead);
// kernel-controllable share ~5-7us. 2-kernel split was 1us WORSE (extra
// launch). => single launch, 1024 blocks x 256 threads (4 blocks/CU for
// latency hiding), 8 z-rows/block, redundant per-block xW (x is L2-resident).

union F4 { float4 v; float f[4]; };

// LDS bank swizzle for W rows (phase-C reads are d-strided float4s).
__device__ __forceinline__ int sw(int r) { return r + (r >> 3); }

__global__ void __launch_bounds__(256) gam_fused(
    const float* __restrict__ z, const float* __restrict__ x,
    const float* __restrict__ W, const float* __restrict__ b,
    float4* __restrict__ out4)
{
    __shared__ float4 Wf[292];        // swizzled [256 rows][4 heads]
    __shared__ float4 tpart[2][128];  // xW partials (two d-halves)
    __shared__ float4 tvec[128];      // t[m] = xW + b
    __shared__ float4 zw[8];          // zW for this block's 8 rows

    const int t   = threadIdx.x;
    const int blk = blockIdx.x;

    // ---- z slice: 8 rows x 128 = 256 float4, one per thread ----
    // chunk t: row = t>>5, d0 = (t&31)*4
    const float4* zp = (const float4*)(z + (size_t)blk * 8 * 128);
    F4 a0; a0.v = zp[t];

    // ---- W -> LDS (swizzled) ----
    Wf[sw(t)] = ((const float4*)W)[t];
    __syncthreads();

    // ---- phase A: xW partials t[m][h] = sum_d x[d][m]*W2[d][h] ----
    // m = t&127, half = t>>7; x column reads coalesced, L2-resident.
    {
        const int m    = t & 127;
        const int half = t >> 7;
        const float* xp = x + (size_t)(half * 64) * 128 + m;
        float4 acc = make_float4(0.f, 0.f, 0.f, 0.f);
#pragma unroll 8
        for (int dd = 0; dd < 64; ++dd) {
            float  xv = xp[dd * 128];
            float4 w  = Wf[sw(128 + half * 64 + dd)];  // wave-uniform broadcast
            acc.x = fmaf(xv, w.x, acc.x);
            acc.y = fmaf(xv, w.y, acc.y);
            acc.z = fmaf(xv, w.z, acc.z);
            acc.w = fmaf(xv, w.w, acc.w);
        }
        tpart[half][m] = acc;
    }

    // ---- phase C: zW for 8 rows; 32 lanes (same t>>5) share a row ----
    {
        const int d0 = (t & 31) * 4;
        float4 p0 = make_float4(0.f, 0.f, 0.f, 0.f);
#pragma unroll
        for (int j = 0; j < 4; ++j) {
            float4 w = Wf[sw(d0 + j)];   // W1 rows
            p0.x = fmaf(a0.f[j], w.x, p0.x);
            p0.y = fmaf(a0.f[j], w.y, p0.y);
            p0.z = fmaf(a0.f[j], w.z, p0.z);
            p0.w = fmaf(a0.f[j], w.w, p0.w);
        }
#pragma unroll
        for (int off = 16; off; off >>= 1) {   // stays in 32-lane row-groups
            p0.x += __shfl_xor(p0.x, off);
            p0.y += __shfl_xor(p0.y, off);
            p0.z += __shfl_xor(p0.z, off);
            p0.w += __shfl_xor(p0.w, off);
        }
        if ((t & 31) == 0) zw[t >> 5] = p0;
    }
    __syncthreads();

    // ---- combine t = tpart0 + tpart1 + b ----
    if (t < 128) {
        float4 bv = *(const float4*)b;
        float4 q0 = tpart[0][t];
        float4 q1 = tpart[1][t];
        float4 tv;
        tv.x = q0.x + q1.x + bv.x;
        tv.y = q0.y + q1.y + bv.y;
        tv.z = q0.z + q1.z + bv.z;
        tv.w = q0.w + q1.w + bv.w;
        tvec[t] = tv;
    }
    __syncthreads();

    // ---- phase D: out4[row][m] = relu(tvec[m] + zw[row]) ----
    // chunk c = it*256+t: row = it*2+(t>>7) (wave-uniform), m = t&127 (invariant)
    {
        const float4 tq = tvec[t & 127];
        float4* op = out4 + (size_t)blk * 1024;   // 8 rows x 128 float4
#pragma unroll
        for (int it = 0; it < 4; ++it) {
            const int row = it * 2 + (t >> 7);
            float4 s = zw[row];                    // LDS broadcast
            float4 v;
            v.x = fmaxf(tq.x + s.x, 0.f);
            v.y = fmaxf(tq.y + s.y, 0.f);
            v.z = fmaxf(tq.z + s.z, 0.f);
            v.w = fmaxf(tq.w + s.w, 0.f);
            op[it * 256 + t] = v;                  // 16B coalesced store
        }
    }
}

extern "C" void kernel_launch(void* const* d_in, const int* in_sizes, int n_in,
                              void* d_out, int out_size, void* d_ws, size_t ws_size,
                              hipStream_t stream) {
    const float* z = (const float*)d_in[0];
    const float* x = (const float*)d_in[1];
    const float* W = (const float*)d_in[2];
    const float* b = (const float*)d_in[3];
    gam_fused<<<1024, 256, 0, stream>>>(z, x, W, b, (float4*)d_out);
}